// Round 5
// baseline (452.345 us; speedup 1.0000x reference)
//
#include <hip/hip_runtime.h>

// Graph WaveNet GCN on gfx950 — fused propagate+project, 2-blocks/CU pipeline.
// out[n,o,w,l] = b[o] + sum_{blk,c} W[o,blk*32+c] * H_blk[n,c,w,l]
//   H_0 = x,  H_{1+p} = x @ P_p over v,  P = [A0, A0^2, A1, A1^2, A2, A2^2]
//
// Xt row order: m = (b*13 + l)*32 + c  -> 128-row tile = 4 complete channel
// groups, so each block projects its own Y-tile through LDS (Y never hits HBM).
//
// fused_gcn: 256 threads / 4 waves, tile 128m x 64w x 2p. LDS 64 KB ->
// TWO independent blocks per CU (disjoint barriers overlap each other's
// stalls). K-loop: triple-buffered staging, stage kt+2 each kt,
// s_waitcnt vmcnt(4) (never 0 mid-loop), one s_barrier per kt. W in regs.
// sched_barrier(0) after every s_barrier: raw s_barrier is NOT a compiler
// fence (rule #18) — without the pin, ds_read/ds_write can migrate across
// it and race with the triple-buffer staging (round-4 failure mode).
//
// ws layout (bytes):
//   XT   @ 0          : Xt[m][v] bf16, 26624 x 512
//   BT   @ 27262976   : Bt[p][w][v] bf16 (P_p^T), 6 x 512x512
//   ABF  @ 30408704   : A_s bf16 row-major, 3 x 512x512
//   WBF  @ 31981568   : W bf16 [64][224]

typedef unsigned short u16;
typedef unsigned int   u32;
typedef __bf16 bf16x8 __attribute__((ext_vector_type(8)));
typedef float  f32x4  __attribute__((ext_vector_type(4)));
typedef u16    u16x8  __attribute__((ext_vector_type(8)));

#define DEVI static __device__ __forceinline__

#define NV   512
#define NL   13
#define SZA  262144L        // 512*512

#define VMCNT(n) asm volatile("s_waitcnt vmcnt(" #n ")" ::: "memory")
#define LGKM0    asm volatile("s_waitcnt lgkmcnt(0)" ::: "memory")
#define BAR()    __builtin_amdgcn_s_barrier()
#define SB0      __builtin_amdgcn_sched_barrier(0)

DEVI u16 f2bf(float f) {
  union { float f; u32 u; } v; v.f = f;
  u32 u = v.u;
  return (u16)((u + 0x7fffu + ((u >> 16) & 1u)) >> 16);  // RNE
}

DEVI void gl2lds16(const void* g, void* l) {
  __builtin_amdgcn_global_load_lds((__attribute__((address_space(1))) void*)g,
                                   (__attribute__((address_space(3))) void*)l, 16, 0, 0);
}

// ---------------------------------------------------------------- merged prep
// bid < 2048          : transpose x[b][c][v][l] -> Xt[(b*13+l)*32+c][v] bf16
// 2048 <= bid < 2816  : supports -> ABF (bf16 row-major) + BT (transposed bf16)
// bid >= 2816         : W -> bf16
__global__ __launch_bounds__(256) void prep_all(const float* __restrict__ x,
                                                const float* __restrict__ A0,
                                                const float* __restrict__ A1,
                                                const float* __restrict__ A2,
                                                const float* __restrict__ W,
                                                u16* __restrict__ XT,
                                                u16* __restrict__ BT,
                                                u16* __restrict__ ABF,
                                                u16* __restrict__ WBF) {
  const int bid = blockIdx.x, tid = threadIdx.x;
  if (bid < 2048) {
    __shared__ __align__(16) float tile[NV * NL];  // 26.6 KB
    const int b = bid >> 5, c = bid & 31;
    const float4* src4 = (const float4*)(x + (long)bid * (NV * NL));
    float4* t4 = (float4*)tile;
    for (int i = tid; i < (NV * NL) / 4; i += 256) t4[i] = src4[i];
    __syncthreads();
    for (int j = tid; j < NL * 256; j += 256) {
      const int l = j >> 8, v = (j & 255) * 2;
      const long row = (long)(b * 13 + l) * 32 + c;
      const u32 lo = f2bf(tile[v * NL + l]);
      const u32 hi = f2bf(tile[(v + 1) * NL + l]);
      *(u32*)&XT[row * 512 + v] = lo | (hi << 16);
    }
  } else if (bid < 2816) {
    const int idx = bid - 2048;
    const int s = idx >> 8, rem = idx & 255;
    const float* A = (s == 0) ? A0 : ((s == 1) ? A1 : A2);
    u16* abf = ABF + (long)s * SZA;
    u16* bt  = BT + (long)(2 * s) * SZA;
    __shared__ float t[32][33];
    const int v0 = (rem >> 4) * 32, w0 = (rem & 15) * 32;
    for (int i = tid; i < 1024; i += 256) {
      const int r = i >> 5, cc = i & 31;
      const float val = A[(long)(v0 + r) * 512 + w0 + cc];
      t[r][cc] = val;
      abf[(long)(v0 + r) * 512 + w0 + cc] = f2bf(val);
    }
    __syncthreads();
    for (int i = tid; i < 1024; i += 256) {
      const int r = i >> 5, cc = i & 31;
      bt[(long)(w0 + r) * 512 + v0 + cc] = f2bf(t[cc][r]);
    }
  } else {
    const int i = (bid - 2816) * 256 + tid;
    WBF[i] = f2bf(W[i]);
  }
}

// ---------------------------------------------------------------- small NT GEMM (P^2)
__global__ __launch_bounds__(256) void gemm512(const u16* __restrict__ Ag,
                                               const u16* __restrict__ Bg,
                                               u16* __restrict__ Cg,
                                               long aZ, long bZ, long cZ) {
  __shared__ __align__(16) u16 As[128 * 32];
  __shared__ __align__(16) u16 Bs[128 * 32];
  const int p = blockIdx.z;
  const u16* A = Ag + (long)p * aZ;
  const u16* B = Bg + (long)p * bZ;
  u16*       C = Cg + (long)p * cZ;
  const int m0 = blockIdx.y * 128, n0 = blockIdx.x * 128;
  const int tid = threadIdx.x;
  const int lane = tid & 63, wid = tid >> 6;
  const int wm = wid >> 1, wn = wid & 1;
  const int lr = lane & 15, lq = lane >> 4;
  const int srow = lane >> 2, skq = lane & 3;

  f32x4 acc[4][4] = {};

  for (int kt = 0; kt < 16; ++kt) {
    const int k0 = kt * 32;
    __syncthreads();
#pragma unroll
    for (int j = 0; j < 2; ++j) {
      const int rb = wid * 32 + j * 16;
      gl2lds16(A + (long)(m0 + rb + srow) * 512 + (k0 + skq * 8), &As[rb * 32]);
      gl2lds16(B + (long)(n0 + rb + srow) * 512 + (k0 + skq * 8), &Bs[rb * 32]);
    }
    __syncthreads();
    bf16x8 af[4], bv[4];
#pragma unroll
    for (int t = 0; t < 4; ++t) {
      af[t] = *(const bf16x8*)&As[(wm * 64 + t * 16 + lr) * 32 + lq * 8];
      bv[t] = *(const bf16x8*)&Bs[(wn * 64 + t * 16 + lr) * 32 + lq * 8];
    }
#pragma unroll
    for (int i = 0; i < 4; ++i)
#pragma unroll
      for (int j = 0; j < 4; ++j)
        acc[i][j] = __builtin_amdgcn_mfma_f32_16x16x32_bf16(af[i], bv[j], acc[i][j], 0, 0, 0);
  }
#pragma unroll
  for (int i = 0; i < 4; ++i) {
    const int mr = m0 + wm * 64 + i * 16 + lq * 4;
#pragma unroll
    for (int j = 0; j < 4; ++j) {
      const int nc = n0 + wn * 64 + j * 16 + lr;
#pragma unroll
      for (int r = 0; r < 4; ++r)
        C[(long)(mr + r) * 512 + nc] = f2bf(acc[i][j][r]);
    }
  }
}

// ---------------------------------------------------------------- fused GCN
// One block: 128 m-rows (4 channel groups) x 64 w, 2 p's per pass. 256 thr.
// LDS 64 KB -> 2 blocks/CU. Wave tile (main gemm): 64m x 32w x 2p.
// Projection: wave = channel group g, full 64 w.
__global__ __launch_bounds__(256, 2) void fused_gcn(const u16* __restrict__ XT,
                                                    const u16* __restrict__ BT,
                                                    const u16* __restrict__ WBF,
                                                    const float* __restrict__ bias,
                                                    float* __restrict__ out) {
  __shared__ __align__(16) u16 As[3][128 * 32];  // 24 KB  [m-row][k-chunk swz]
  __shared__ __align__(16) u16 Bs[3][128 * 32];  // 24 KB  [p*64+w-row][k swz]
  __shared__ __align__(16) u16 Yt[64 * 128];     // 16 KB  [w][m swz]

  // grid decode: XCD k = P%8 exclusively owns b in [8k,8k+8)
  // (208 blocks per XCD = 26 m-panels * 8 w-tiles, exact).
  const int P = blockIdx.x;
  const int xcd = P & 7, inner = P >> 3;
  const int ym = xcd * 26 + (inner >> 3);   // m-panel 0..207
  const int m0 = ym * 128;
  const int w0 = (inner & 7) * 64;

  const int tid  = threadIdx.x;
  const int lane = tid & 63, wid = tid >> 6;
  const int lr = lane & 15, lq = lane >> 4;
  const int wm = wid >> 1, ww = wid & 1;    // main gemm: m-half, w-half
  const int g  = wid;                       // projection: channel group
  const int co = (lq ^ ((lr >> 1) & 3)) * 8;               // swizzled read chunk
  const int sr = lane >> 2;                                // staging row in 16-blk
  const int sc = ((lane & 3) ^ ((lane >> 3) & 3)) * 8;     // pre-swz global chunk

  // ---- X tile -> Yt (transposed + chunk-swizzled): Yt[w][m] = Xt[m0+m][w0+w]
  for (int i = tid; i < 1024; i += 256) {
    const int row = i >> 3, c8 = (i & 7) * 8;
    const u16x8 d = *(const u16x8*)&XT[(long)(m0 + row) * 512 + w0 + c8];
#pragma unroll
    for (int z = 0; z < 8; ++z) {
      const int w = c8 + z;
      Yt[w * 128 + ((((row >> 3) ^ (w & 7)) << 3) | (row & 7))] = d[z];
    }
  }
  __syncthreads();   // full fence: clean slate before counted-vmcnt region

  f32x4 oacc[4][4] = {};   // [o-frag][w-frag] for group g

#define STAGE(Bp0_, Bp1_, kk, bb) do {                                         \
    const int kc_ = (kk) * 32 + sc;                                            \
    const u16* bsrc_ = (wid < 2) ? (Bp0_) : (Bp1_);                            \
    _Pragma("unroll")                                                          \
    for (int t_ = 0; t_ < 2; ++t_) {                                           \
      gl2lds16(XT + (long)(m0 + wid * 32 + t_ * 16 + sr) * 512 + kc_,          \
               &As[bb][(wid * 32 + t_ * 16) * 32]);                            \
      gl2lds16(bsrc_ + (long)(w0 + (wid & 1) * 32 + t_ * 16 + sr) * 512 + kc_, \
               &Bs[bb][(wid * 32 + t_ * 16) * 32]);                            \
    }                                                                          \
  } while (0)

#define PROJ(AF_) do {                                                         \
    bf16x8 pbv_[4];                                                            \
    _Pragma("unroll")                                                          \
    for (int wj = 0; wj < 4; ++wj) {                                           \
      const int w_ = wj * 16 + lr;                                             \
      pbv_[wj] = *(const bf16x8*)&Yt[w_ * 128 + (((g * 4 + lq) ^ (w_ & 7)) << 3)]; \
    }                                                                          \
    _Pragma("unroll")                                                          \
    for (int oi = 0; oi < 4; ++oi)                                             \
      _Pragma("unroll")                                                        \
      for (int wj = 0; wj < 4; ++wj)                                           \
        oacc[oi][wj] = __builtin_amdgcn_mfma_f32_16x16x32_bf16((AF_)[oi], pbv_[wj], oacc[oi][wj], 0, 0, 0); \
  } while (0)

#define WRB(ac) do {                                                           \
    _Pragma("unroll")                                                          \
    for (int i = 0; i < 2; ++i)                                                \
      _Pragma("unroll")                                                        \
      for (int j = 0; j < 4; ++j)                                              \
        _Pragma("unroll")                                                      \
        for (int r = 0; r < 4; ++r) {                                          \
          const int w_ = ww * 32 + i * 16 + lq * 4 + r;                        \
          const int m_ = wm * 64 + j * 16 + lr;                                \
          Yt[w_ * 128 + ((((m_ >> 3) ^ (w_ & 7)) << 3) | (m_ & 7))] = f2bf(ac[i][j][r]); \
        }                                                                      \
  } while (0)

  for (int pass = 0; pass < 3; ++pass) {
    const u16* Bp0 = BT + (long)(2 * pass) * SZA;
    const u16* Bp1 = BT + (long)(2 * pass + 1) * SZA;
    // W fragments for this pass's two concat blocks (kept in registers)
    bf16x8 afA[4], afB[4];
#pragma unroll
    for (int oi = 0; oi < 4; ++oi) {
      afA[oi] = *(const bf16x8*)&WBF[(oi * 16 + lr) * 224 + (2 * pass) * 32 + lq * 8];
      afB[oi] = *(const bf16x8*)&WBF[(oi * 16 + lr) * 224 + (2 * pass + 1) * 32 + lq * 8];
    }
    STAGE(Bp0, Bp1, 0, 0);          // prefetch kt=0  (4 loads in flight)
    STAGE(Bp0, Bp1, 1, 1);          // prefetch kt=1  (8 in flight)
    PROJ(afA);                      // LDS-only: overlaps staging latency
    f32x4 accA[2][4] = {}, accB[2][4] = {};
#pragma unroll
    for (int kt = 0; kt < 16; ++kt) {
      if (kt == 15) { VMCNT(0); } else { VMCNT(4); }   // wait oldest quad only
      BAR(); SB0;                  // pin: nothing migrates across the barrier
      if (kt < 14) STAGE(Bp0, Bp1, kt + 2, (kt + 2) % 3);
      const int buf = kt % 3;
      bf16x8 a0[2], a1[2], bv[4];
#pragma unroll
      for (int i = 0; i < 2; ++i) {
        a0[i] = *(const bf16x8*)&Bs[buf][(     ww * 32 + i * 16 + lr) * 32 + co];
        a1[i] = *(const bf16x8*)&Bs[buf][(64 + ww * 32 + i * 16 + lr) * 32 + co];
      }
#pragma unroll
      for (int j = 0; j < 4; ++j)
        bv[j] = *(const bf16x8*)&As[buf][(wm * 64 + j * 16 + lr) * 32 + co];
      LGKM0; SB0;                  // all reads landed; MFMAs can't hoist above
#pragma unroll
      for (int i = 0; i < 2; ++i)
#pragma unroll
        for (int j = 0; j < 4; ++j) {
          accA[i][j] = __builtin_amdgcn_mfma_f32_16x16x32_bf16(a0[i], bv[j], accA[i][j], 0, 0, 0);
          accB[i][j] = __builtin_amdgcn_mfma_f32_16x16x32_bf16(a1[i], bv[j], accB[i][j], 0, 0, 0);
        }
      SB0;                         // reads of next iter can't hoist into MFMAs
    }
    WRB(accA);  LGKM0; BAR(); SB0;
    PROJ(afB);  LGKM0; BAR(); SB0;
    WRB(accB);  LGKM0; BAR(); SB0;
  }
  // tail: project Y[5] with W block 6
  bf16x8 af6[4];
#pragma unroll
  for (int oi = 0; oi < 4; ++oi)
    af6[oi] = *(const bf16x8*)&WBF[(oi * 16 + lr) * 224 + 6 * 32 + lq * 8];
  PROJ(af6);

  // epilogue: out[((b*64+o)*512+w)*13 + l] for this wave's (b,l) = group g
  const int bl = ym * 4 + g;
  const int b  = bl / 13, l = bl - b * 13;
  float* outb = out + (long)b * (64L * 512 * 13) + l;
#pragma unroll
  for (int oi = 0; oi < 4; ++oi) {
    const f32x4 bi = *(const f32x4*)&bias[oi * 16 + lq * 4];
#pragma unroll
    for (int wj = 0; wj < 4; ++wj) {
      const int w = w0 + wj * 16 + lr;
      const long base = ((long)(oi * 16 + lq * 4) * 512 + w) * 13;
#pragma unroll
      for (int r = 0; r < 4; ++r)
        outb[base + (long)r * (512 * 13)] = oacc[oi][wj][r] + bi[r];
    }
  }
#undef STAGE
#undef PROJ
#undef WRB
}

extern "C" void kernel_launch(void* const* d_in, const int* in_sizes, int n_in,
                              void* d_out, int out_size, void* d_ws, size_t ws_size,
                              hipStream_t stream) {
  const float* x  = (const float*)d_in[0];
  const float* s0 = (const float*)d_in[1];
  const float* s1 = (const float*)d_in[2];
  const float* s2 = (const float*)d_in[3];
  const float* W  = (const float*)d_in[4];
  const float* b  = (const float*)d_in[5];
  float* out = (float*)d_out;

  char* ws = (char*)d_ws;
  u16* XT  = (u16*)(ws);
  u16* BT  = (u16*)(ws + 27262976L);
  u16* ABF = (u16*)(ws + 30408704L);
  u16* WBF = (u16*)(ws + 31981568L);

  prep_all<<<dim3(2872), 256, 0, stream>>>(x, s0, s1, s2, W, XT, BT, ABF, WBF);
  // Bt[2s+1] = (A_s^2)^T = Bt[2s] (NT) ABF[s]
  gemm512<<<dim3(4, 4, 3), 256, 0, stream>>>(BT, ABF, BT + SZA,
                                             2L * SZA, 1L * SZA, 2L * SZA);
  fused_gcn<<<dim3(1664), 256, 0, stream>>>(XT, BT, WBF, b, out);
}